// Round 8
// baseline (794.665 us; speedup 1.0000x reference)
//
#include <hip/hip_runtime.h>

#define TT 128
#define BB 32
#define II 128
#define HH 320
#define OO 32
#define GG 8
#define HPAD 129   // s_hist row pitch (pad: read down-column in poll phase)

static __device__ __forceinline__ float fexp2(float x) { return __builtin_amdgcn_exp2f(x); }
static __device__ __forceinline__ float frcp(float x)  { return __builtin_amdgcn_rcpf(x); }

// tanh for x >= 0: 1 - 2/(e^{2x}+1)
static __device__ __forceinline__ float tanh_pos(float x) {
    float e = fexp2(x * 2.8853900817779268f);
    return 1.0f - 2.0f * frcp(e + 1.0f);
}

// Agent-scope relaxed ops: coherence point = MALL. Rounds 3/6 showed every
// cross-block handshake costs ~1 MALL RTT regardless of mechanism (plain sc1
// vs atomics) -- so this kernel HIDES the latency (2 batches/block ping-pong)
// instead of trying to shorten it.
static __device__ __forceinline__ void pub_store(float* p, float v) {
    __hip_atomic_store(p, v, __ATOMIC_RELAXED, __HIP_MEMORY_SCOPE_AGENT);
}
static __device__ __forceinline__ float gath_load(const float* p) {
    return __hip_atomic_load(p, __ATOMIC_RELAXED, __HIP_MEMORY_SCOPE_AGENT);
}

__global__ __launch_bounds__(512, 2)
void leaky_rnn_kernel(const float* __restrict__ x, const float* __restrict__ Rs,
                      const float* __restrict__ Wx2h, const float* __restrict__ Wh2h,
                      const float* __restrict__ bh2h, const float* __restrict__ Wh2o,
                      const float* __restrict__ bh2o, const float* __restrict__ Wattn,
                      const float* __restrict__ battn, const float* __restrict__ cplas,
                      float* __restrict__ out, float* __restrict__ hs,
                      unsigned* __restrict__ ctr)
{
    const int tid  = threadIdx.x;
    const int q    = blockIdx.x;   // 128 blocks
    const int bA   = q & 15;       // batches bA and bA+16 share this block
    const int bB   = bA + 16;
    const int sub  = q >> 4;       // 8 blocks per batch-pair, 40 rows each
    const int w    = tid >> 6;     // wave 0..7
    const int lane = tid & 63;
    const int h0   = sub * 40;

    __shared__ float s_outA[HH], s_outB[HH];     // previous outputs
    __shared__ float s_logitA[GG], s_logitB[GG];
    __shared__ float s_histA[40 * HPAD];         // own rows' true values, all t
    __shared__ float s_histB[40 * HPAD];
    __shared__ float s_hs[16 * HH];              // readout staging (reused A then B)

    // ---- one-time init ----
    // attn weights for group w at this lane's 5 columns (loop-invariant -> regs)
    float ea[5];
#pragma unroll
    for (int k = 0; k < 5; ++k) {
        int j = lane + 64 * k;
        float m = (j < 256) ? 1.f : (j == 256 ? -1.f : 0.f);  // mask_a (zc=63!)
        ea[k] = fmaxf(Wattn[w * HH + j], 0.f) * m;
    }
    if (tid < HH) { s_outA[tid] = 0.f; s_outB[tid] = 0.f; }

    // plastic weights in registers, both batches (identical initial values)
    float wxA[5][2], whA[5][5], wxB[5][2], whB[5][5];
    float stA[5], stB[5], bh[5];
    int hrow[5];
#pragma unroll
    for (int r = 0; r < 5; ++r) {
        int h = h0 + w * 5 + r;
        hrow[r] = h; bh[r] = bh2h[h]; stA[r] = 0.f; stB[r] = 0.f;
#pragma unroll
        for (int c = 0; c < 2; ++c) {
            float v = fmaxf(Wx2h[h * II + lane + 64 * c], 0.f);
            wxA[r][c] = v; wxB[r][c] = v;
        }
#pragma unroll
        for (int c = 0; c < 5; ++c) {
            int j = lane + 64 * c;
            float v = fmaxf(Wh2h[h * HH + j], 0.f);
            v = (c == 4) ? -v : v;          // sign_h: j>=256 -> -1
            // diagonal poison: decays *0.9/step (>= -3e24 at t=127), relu-dead
            // forever; stored diag never affects any output (mask_h zeroes it
            // in the dot), so no per-step cndmask needed.
            v = (j == h) ? -1e30f : v;
            whA[r][c] = v; whB[r][c] = v;
        }
    }
    float batt = battn[w];
    float c0 = fabsf(cplas[0]), c1 = fabsf(cplas[1]), c2 = fabsf(cplas[2]);
    float c3 = fabsf(cplas[3]), c4 = fabsf(cplas[4]), c5 = fabsf(cplas[5]);
    const float AX = 0.2f, OMX = 0.8f, AW = 0.1f, OMW = 0.9f;
    const float L2E = 1.4426950408889634f;
    const int g0 = lane >> 4;   // this lane's attn group for col=lane (col+64 -> g0+4)

    __syncthreads();

    // prefetch t=0 inputs
    float xA0 = x[bA * II + lane], xA1 = x[bA * II + lane + 64];
    float xB0 = x[bB * II + lane], xB1 = x[bB * II + lane + 64];
    float RvA = Rs[bA], RvB = Rs[bB];

#pragma unroll 1
    for (int t = 0; t < TT; ++t) {
        // ---- attention logits, both batches (wave w = group w) ----
        float lpA = 0.f, lpB = 0.f;
#pragma unroll
        for (int k = 0; k < 5; ++k) {
            lpA = fmaf(ea[k], s_outA[lane + 64 * k], lpA);
            lpB = fmaf(ea[k], s_outB[lane + 64 * k], lpB);
        }
#pragma unroll
        for (int m = 1; m < 64; m <<= 1) {
            lpA += __shfl_xor(lpA, m, 64);
            lpB += __shfl_xor(lpB, m, 64);
        }
        if (lane == 0) { s_logitA[w] = lpA + batt; s_logitB[w] = lpB + batt; }
        __syncthreads();

        float noA[5], ocA[5], xmA0, xmA1;
        float noB[5], ocB[5], xmB0, xmB1;

        // ---------- batch A: softmax (per-lane) + dots + publish ----------
        {
            float lg[8];
#pragma unroll
            for (int g = 0; g < 8; ++g) lg[g] = s_logitA[g];
            float mx = lg[0];
#pragma unroll
            for (int g = 1; g < 8; ++g) mx = fmaxf(mx, lg[g]);
            float se = 0.f, eg[8];
#pragma unroll
            for (int g = 0; g < 8; ++g) { eg[g] = fexp2((lg[g] - mx) * L2E); se += eg[g]; }
            float k8 = 8.f * frcp(se);
            xmA0 = xA0 * eg[g0] * k8;  xmA1 = xA1 * eg[g0 + 4] * k8;
#pragma unroll
            for (int c = 0; c < 5; ++c) ocA[c] = s_outA[lane + 64 * c];
            float oc4n = -ocA[4];
#pragma unroll
            for (int r = 0; r < 5; ++r) {
                float p = fmaxf(wxA[r][0], 0.f) * xmA0;
                p = fmaf(fmaxf(wxA[r][1], 0.f), xmA1, p);
#pragma unroll
                for (int c = 0; c < 5; ++c) {
                    float so = (c == 4) ? oc4n : ocA[c];
                    p = fmaf(fmaxf(whA[r][c], 0.f), so, p);
                }
#pragma unroll
                for (int m = 1; m < 64; m <<= 1) p += __shfl_xor(p, m, 64);
                stA[r] = fmaf(stA[r], OMX, (p + bh[r]) * AX);
                noA[r] = tanh_pos(fmaxf(stA[r], 0.f));
                if (lane == r) {
                    // biased publish [2,3): poison 0xAA.. and memset-0 are <1
                    pub_store(&hs[(t * BB + bA) * HH + hrow[r]], noA[r] + 2.0f);
                    s_histA[(w * 5 + r) * HPAD + t] = noA[r];
                }
            }
        }
        // ---------- batch B ----------
        {
            float lg[8];
#pragma unroll
            for (int g = 0; g < 8; ++g) lg[g] = s_logitB[g];
            float mx = lg[0];
#pragma unroll
            for (int g = 1; g < 8; ++g) mx = fmaxf(mx, lg[g]);
            float se = 0.f, eg[8];
#pragma unroll
            for (int g = 0; g < 8; ++g) { eg[g] = fexp2((lg[g] - mx) * L2E); se += eg[g]; }
            float k8 = 8.f * frcp(se);
            xmB0 = xB0 * eg[g0] * k8;  xmB1 = xB1 * eg[g0 + 4] * k8;
#pragma unroll
            for (int c = 0; c < 5; ++c) ocB[c] = s_outB[lane + 64 * c];
            float oc4n = -ocB[4];
#pragma unroll
            for (int r = 0; r < 5; ++r) {
                float p = fmaxf(wxB[r][0], 0.f) * xmB0;
                p = fmaf(fmaxf(wxB[r][1], 0.f), xmB1, p);
#pragma unroll
                for (int c = 0; c < 5; ++c) {
                    float so = (c == 4) ? oc4n : ocB[c];
                    p = fmaf(fmaxf(whB[r][c], 0.f), so, p);
                }
#pragma unroll
                for (int m = 1; m < 64; m <<= 1) p += __shfl_xor(p, m, 64);
                stB[r] = fmaf(stB[r], OMX, (p + bh[r]) * AX);
                noB[r] = tanh_pos(fmaxf(stB[r], 0.f));
                if (lane == r) {
                    pub_store(&hs[(t * BB + bB) * HH + hrow[r]], noB[r] + 2.0f);
                    s_histB[(w * 5 + r) * HPAD + t] = noB[r];
                }
            }
        }

        // ---- plastic weight updates + prefetch (hides publish propagation) ----
        if (t < TT - 1) {
            float A_ = AW * RvA;
            float a0 = A_*c0, a1 = A_*c1, a2 = A_*c2, a3 = A_*c3, a4 = A_*c4, a5 = A_*c5;
#pragma unroll
            for (int r = 0; r < 5; ++r) {
                float u = fmaf(a2, noA[r], a0), v = a1 * noA[r];
                float pp = fmaf(a5, noA[r], a3), qq = a4 * noA[r];
                wxA[r][0] = fmaf(wxA[r][0], OMW, fmaf(u, xmA0, v));
                wxA[r][1] = fmaf(wxA[r][1], OMW, fmaf(u, xmA1, v));
#pragma unroll
                for (int c = 0; c < 5; ++c)
                    whA[r][c] = fmaf(whA[r][c], OMW, fmaf(pp, ocA[c], qq));
            }
            float B_ = AW * RvB;
            float e0 = B_*c0, e1 = B_*c1, e2 = B_*c2, e3 = B_*c3, e4 = B_*c4, e5 = B_*c5;
#pragma unroll
            for (int r = 0; r < 5; ++r) {
                float u = fmaf(e2, noB[r], e0), v = e1 * noB[r];
                float pp = fmaf(e5, noB[r], e3), qq = e4 * noB[r];
                wxB[r][0] = fmaf(wxB[r][0], OMW, fmaf(u, xmB0, v));
                wxB[r][1] = fmaf(wxB[r][1], OMW, fmaf(u, xmB1, v));
#pragma unroll
                for (int c = 0; c < 5; ++c)
                    whB[r][c] = fmaf(whB[r][c], OMW, fmaf(pp, ocB[c], qq));
            }
            int tn = t + 1;
            xA0 = x[(tn * BB + bA) * II + lane]; xA1 = x[(tn * BB + bA) * II + lane + 64];
            xB0 = x[(tn * BB + bB) * II + lane]; xB1 = x[(tn * BB + bB) * II + lane + 64];
            RvA = Rs[tn * BB + bA]; RvB = Rs[tn * BB + bB];
        }

        __syncthreads();   // all reads of s_out done -> safe to overwrite

        // ---- combined gather: poll A and B concurrently (independent targets;
        //      A's data ~2 compute-phases old, B's ~1 -> mostly first-hit) ----
        if (t < TT - 1 && tid < HH) {
            float vA, vB;
            if (tid >= h0 && tid < h0 + 40) {
                vA = s_histA[(tid - h0) * HPAD + t];
                vB = s_histB[(tid - h0) * HPAD + t];
            } else {
                const float* pA = &hs[(t * BB + bA) * HH + tid];
                const float* pB = &hs[(t * BB + bB) * HH + tid];
                vA = gath_load(pA); vB = gath_load(pB);
                int guard = 0;
                while (vA < 1.f || vB < 1.f) {
                    if (vA < 1.f) vA = gath_load(pA);
                    if (vB < 1.f) vB = gath_load(pB);
                    if (++guard > 300000) break;   // failsafe: never hang
                }
                vA -= 2.f; vB -= 2.f;
            }
            s_outA[tid] = vA; s_outB[tid] = vB;
        }
        __syncthreads();
    }

    // ======== final phase ========
    // Barrier A among the 8 sibling blocks (same set serves bA and bB):
    // everyone's t-loop done, all publishes drained (syncthreads above).
    if (tid == 0) {
        __hip_atomic_fetch_add(&ctr[bA * 32], 1u, __ATOMIC_RELAXED, __HIP_MEMORY_SCOPE_AGENT);
        int guard = 0;
        while (__hip_atomic_load(&ctr[bA * 32], __ATOMIC_RELAXED, __HIP_MEMORY_SCOPE_AGENT) < 8u) {
            if (++guard > 2000000) break;
            __builtin_amdgcn_s_sleep(1);
        }
    }
    __syncthreads();

    // readout for both batches (s_hs reused, barrier-separated)
#pragma unroll 1
    for (int pass = 0; pass < 2; ++pass) {
        int b = pass ? bB : bA;
        for (int idx = tid; idx < 16 * HH; idx += 512) {
            int tl = idx / HH, h = idx % HH;
            int t_g = sub * 16 + tl;
            s_hs[idx] = gath_load(&hs[(t_g * BB + b) * HH + h]) - 2.0f;
        }
        __syncthreads();
        {
            int t_loc = tid >> 5;          // 0..15
            int o     = tid & 31;
            int t_g   = sub * 16 + t_loc;
            const float* hp = &s_hs[t_loc * HH];
            float acc = bh2o[o];
#pragma unroll 4
            for (int h = 0; h < 257; ++h) {          // mask_o zero for h>256 (zc=63)
                float m = (h == 256) ? -1.f : 1.f;
                acc = fmaf(fmaxf(Wh2o[o * HH + h], 0.f) * m, hp[h], acc);
            }
            out[(t_g * BB + b) * OO + o] = frcp(1.f + fexp2(-acc * L2E));
        }
        __syncthreads();
    }

    // Barrier B: all siblings finished READING biased hs -> safe to rewrite
    if (tid == 0) {
        __hip_atomic_fetch_add(&ctr[bA * 32], 1u, __ATOMIC_RELAXED, __HIP_MEMORY_SCOPE_AGENT);
        int guard = 0;
        while (__hip_atomic_load(&ctr[bA * 32], __ATOMIC_RELAXED, __HIP_MEMORY_SCOPE_AGENT) < 16u) {
            if (++guard > 2000000) break;
            __builtin_amdgcn_s_sleep(1);
        }
    }
    __syncthreads();

    // rewrite own rows of hs with TRUE values (both batches)
    for (int idx = tid; idx < 40 * TT; idx += 512) {
        int row = idx >> 7;            // idx / 128
        int t   = idx & 127;
        pub_store(&hs[(t * BB + bA) * HH + h0 + row], s_histA[row * HPAD + t]);
        pub_store(&hs[(t * BB + bB) * HH + h0 + row], s_histB[row * HPAD + t]);
    }
}

extern "C" void kernel_launch(void* const* d_in, const int* in_sizes, int n_in,
                              void* d_out, int out_size, void* d_ws, size_t ws_size,
                              hipStream_t stream) {
    const float* x     = (const float*)d_in[0];
    const float* Rs    = (const float*)d_in[1];
    const float* Wx2h  = (const float*)d_in[2];
    const float* Wh2h  = (const float*)d_in[3];
    const float* bh2h  = (const float*)d_in[4];
    const float* Wh2o  = (const float*)d_in[5];
    const float* bh2o  = (const float*)d_in[6];
    const float* Wattn = (const float*)d_in[7];
    const float* battn = (const float*)d_in[8];
    const float* cplas = (const float*)d_in[9];
    float* out = (float*)d_out;
    float* hs  = out + TT * BB * OO;
    unsigned* ctr = (unsigned*)d_ws;   // 16 pair-groups x 32 uints (128B apart)

    (void)hipMemsetAsync(d_ws, 0, 32 * 32 * sizeof(unsigned), stream);
    hipLaunchKernelGGL(leaky_rnn_kernel, dim3(128), dim3(512), 0, stream,
                       x, Rs, Wx2h, Wh2h, bh2h, Wh2o, bh2o, Wattn, battn, cplas,
                       out, hs, ctr);
}